// Round 2
// baseline (454.949 us; speedup 1.0000x reference)
//
#include <hip/hip_runtime.h>

// GraphSAGE 2-layer pipeline. GEMMs via MFMA bf16 3-term split (fp32-accurate).
// N=50000, E=600000. edge_index int32 (confirmed round 1).

#define NN   50000
#define EE   600000
#define NBLK 49          // ceil(NN/1024)

typedef __attribute__((ext_vector_type(8))) short short8v;   // 8 x bf16 (4 VGPR)
typedef __attribute__((ext_vector_type(4))) float f32x4;

__device__ inline short f2bf_rn(float f) {
    unsigned u = __builtin_bit_cast(unsigned, f);
    unsigned r = u + 0x7FFFu + ((u >> 16) & 1u);
    return (short)(r >> 16);
}

// ---------------- CSR build ----------------

__global__ __launch_bounds__(256) void k_count(const int* __restrict__ ei,
                                               int* __restrict__ counts) {
    int e = blockIdx.x * 256 + threadIdx.x;
    if (e < EE) atomicAdd(&counts[ei[EE + e]], 1);
}

__global__ __launch_bounds__(256) void k_scan_a(const int* __restrict__ counts,
                                                int* __restrict__ bsums) {
    int b = blockIdx.x, t = threadIdx.x;
    int idx = b * 1024 + t * 4;
    int s = 0;
#pragma unroll
    for (int j = 0; j < 4; ++j)
        if (idx + j < NN) s += counts[idx + j];
#pragma unroll
    for (int off = 32; off > 0; off >>= 1) s += __shfl_down(s, off);
    __shared__ int ls[4];
    if ((t & 63) == 0) ls[t >> 6] = s;
    __syncthreads();
    if (t == 0) bsums[b] = ls[0] + ls[1] + ls[2] + ls[3];
}

__global__ void k_scan_b(int* __restrict__ bsums) {
    int t = threadIdx.x;                       // 64 threads
    int v = (t < NBLK) ? bsums[t] : 0;
    int orig = v;
#pragma unroll
    for (int off = 1; off < 64; off <<= 1) {
        int u = __shfl_up(v, off);
        if (t >= off) v += u;
    }
    if (t < NBLK) bsums[t] = v - orig;          // exclusive
}

__global__ __launch_bounds__(256) void k_scan_c(const int* __restrict__ counts,
                                                const int* __restrict__ bsums,
                                                int* __restrict__ rowp) {
    int b = blockIdx.x, t = threadIdx.x;
    int lane = t & 63, wave = t >> 6;
    int idx = b * 1024 + t * 4;
    int c[4], s = 0;
#pragma unroll
    for (int j = 0; j < 4; ++j) {
        c[j] = (idx + j < NN) ? counts[idx + j] : 0;
        s += c[j];
    }
    int sv = s;                                 // inclusive wave scan
#pragma unroll
    for (int off = 1; off < 64; off <<= 1) {
        int u = __shfl_up(sv, off);
        if (lane >= off) sv += u;
    }
    __shared__ int lsum[4];
    if (lane == 63) lsum[wave] = sv;
    __syncthreads();
    int woff = 0;
    for (int wv = 0; wv < wave; ++wv) woff += lsum[wv];
    int base = bsums[b] + woff + (sv - s);      // exclusive prefix for this thread
#pragma unroll
    for (int j = 0; j < 4; ++j) {
        if (idx + j < NN) { rowp[idx + j] = base; base += c[j]; }
    }
}

__global__ __launch_bounds__(256) void k_scatter(const int* __restrict__ ei,
                                                 const int* __restrict__ rowp,
                                                 int* __restrict__ cursor,
                                                 int* __restrict__ col) {
    int e = blockIdx.x * 256 + threadIdx.x;
    if (e < EE) {
        int d = ei[EE + e];
        int p = atomicAdd(&cursor[d], 1);
        col[rowp[d] + p] = ei[e];
    }
}

// ---------------- weight pack: W[K][M] fp32 -> Wt_hi/Wt_lo [M][K] bf16 --------

__global__ __launch_bounds__(256) void k_pack(const float* __restrict__ W,
                                              short* __restrict__ hi,
                                              short* __restrict__ lo,
                                              int K, int M) {
    int idx = blockIdx.x * 256 + threadIdx.x;
    if (idx >= K * M) return;
    int k = idx / M, m = idx - k * M;
    float w = W[idx];
    unsigned u = __builtin_bit_cast(unsigned, w);
    unsigned rn = u + 0x7FFFu + ((u >> 16) & 1u);
    short h = (short)(rn >> 16);
    float hf = __builtin_bit_cast(float, ((unsigned)(unsigned short)h) << 16);
    hi[m * K + k] = h;
    lo[m * K + k] = f2bf_rn(w - hf);
}

// -------- A-row split helper: load 8 fp32, produce bf16 hi (trunc) + lo (rne) --

__device__ inline void load_split_a(const float* __restrict__ ap, bool valid,
                                    short8v& ahi, short8v& alo) {
    float4 a0 = make_float4(0.f, 0.f, 0.f, 0.f), a1 = a0;
    if (valid) {
        a0 = *(const float4*)ap;
        a1 = *(const float4*)(ap + 4);
    }
    float av[8] = {a0.x, a0.y, a0.z, a0.w, a1.x, a1.y, a1.z, a1.w};
#pragma unroll
    for (int j = 0; j < 8; ++j) {
        unsigned u = __builtin_bit_cast(unsigned, av[j]);
        ahi[j] = (short)(u >> 16);                       // truncation: cheap
        float hf = __builtin_bit_cast(float, u & 0xFFFF0000u);
        alo[j] = f2bf_rn(av[j] - hf);                    // residual: rne
    }
}

// ---------------- GEMM pre: h0 = x @ W_pre + b_pre  (K=256, M=128) ------------
// LDS-free MFMA. 4 waves/block, wave owns 16 rows x 128 cols.

__global__ __launch_bounds__(256) void k_gemm_pre(const float* __restrict__ x,
                                                  const short* __restrict__ WtHi,
                                                  const short* __restrict__ WtLo,
                                                  const float* __restrict__ bp,
                                                  float* __restrict__ h0) {
    const int t = threadIdx.x;
    const int wave = t >> 6, lane = t & 63;
    const int r = lane & 15, kb = lane >> 4;
    const int m0 = blockIdx.x * 64 + wave * 16;
    const int row = m0 + r;
    const bool valid = row < NN;

    f32x4 acc[8];
#pragma unroll
    for (int i = 0; i < 8; ++i) acc[i] = (f32x4){0.f, 0.f, 0.f, 0.f};

    for (int k0 = 0; k0 < 256; k0 += 32) {
        const int kOff = k0 + kb * 8;
        short8v ahi, alo;
        load_split_a(&x[(size_t)row * 256 + kOff], valid, ahi, alo);
#pragma unroll
        for (int nt = 0; nt < 8; ++nt) {
            int cof = (nt * 16 + r) * 256 + kOff;
            short8v bhi = *(const short8v*)&WtHi[cof];
            short8v blo = *(const short8v*)&WtLo[cof];
            acc[nt] = __builtin_amdgcn_mfma_f32_16x16x32_bf16(ahi, bhi, acc[nt], 0, 0, 0);
            acc[nt] = __builtin_amdgcn_mfma_f32_16x16x32_bf16(alo, bhi, acc[nt], 0, 0, 0);
            acc[nt] = __builtin_amdgcn_mfma_f32_16x16x32_bf16(ahi, blo, acc[nt], 0, 0, 0);
        }
    }
#pragma unroll
    for (int nt = 0; nt < 8; ++nt) {
        int c = nt * 16 + r;
        float b = bp[c];
#pragma unroll
        for (int j = 0; j < 4; ++j) {
            int orow = m0 + kb * 4 + j;                  // C: row=4*(lane>>4)+reg
            if (orow < NN) h0[(size_t)orow * 128 + c] = acc[nt][j] + b;
        }
    }
}

// ---------------- Dual GEMM: T = A@W1, R = A@W2  (K=128, M in {128,64}) -------

template <int M>
__global__ __launch_bounds__(256) void k_gemm_dual(const float* __restrict__ A,
                                                   const short* __restrict__ W1Hi,
                                                   const short* __restrict__ W1Lo,
                                                   const short* __restrict__ W2Hi,
                                                   const short* __restrict__ W2Lo,
                                                   float* __restrict__ T,
                                                   float* __restrict__ R) {
    constexpr int NT = M / 16;
    const int t = threadIdx.x;
    const int wave = t >> 6, lane = t & 63;
    const int r = lane & 15, kb = lane >> 4;
    const int m0 = blockIdx.x * 64 + wave * 16;
    const int row = m0 + r;
    const bool valid = row < NN;

    f32x4 accT[NT], accR[NT];
#pragma unroll
    for (int i = 0; i < NT; ++i) {
        accT[i] = (f32x4){0.f, 0.f, 0.f, 0.f};
        accR[i] = (f32x4){0.f, 0.f, 0.f, 0.f};
    }

    for (int k0 = 0; k0 < 128; k0 += 32) {
        const int kOff = k0 + kb * 8;
        short8v ahi, alo;
        load_split_a(&A[(size_t)row * 128 + kOff], valid, ahi, alo);
#pragma unroll
        for (int nt = 0; nt < NT; ++nt) {
            int cof = (nt * 16 + r) * 128 + kOff;
            short8v b1h = *(const short8v*)&W1Hi[cof];
            short8v b1l = *(const short8v*)&W1Lo[cof];
            short8v b2h = *(const short8v*)&W2Hi[cof];
            short8v b2l = *(const short8v*)&W2Lo[cof];
            accT[nt] = __builtin_amdgcn_mfma_f32_16x16x32_bf16(ahi, b1h, accT[nt], 0, 0, 0);
            accT[nt] = __builtin_amdgcn_mfma_f32_16x16x32_bf16(alo, b1h, accT[nt], 0, 0, 0);
            accT[nt] = __builtin_amdgcn_mfma_f32_16x16x32_bf16(ahi, b1l, accT[nt], 0, 0, 0);
            accR[nt] = __builtin_amdgcn_mfma_f32_16x16x32_bf16(ahi, b2h, accR[nt], 0, 0, 0);
            accR[nt] = __builtin_amdgcn_mfma_f32_16x16x32_bf16(alo, b2h, accR[nt], 0, 0, 0);
            accR[nt] = __builtin_amdgcn_mfma_f32_16x16x32_bf16(ahi, b2l, accR[nt], 0, 0, 0);
        }
    }
#pragma unroll
    for (int nt = 0; nt < NT; ++nt) {
        int c = nt * 16 + r;
#pragma unroll
        for (int j = 0; j < 4; ++j) {
            int orow = m0 + kb * 4 + j;
            if (orow < NN) {
                T[(size_t)orow * M + c] = accT[nt][j];
                R[(size_t)orow * M + c] = accR[nt][j];
            }
        }
    }
}

// ---------------- Aggregation 1: h1 = relu(mean(t1[src]) + bl1 + r1) ----------

__global__ __launch_bounds__(256) void k_aggr1(const float* __restrict__ t1,
                                               float* __restrict__ r1,
                                               const int* __restrict__ rowp,
                                               const int* __restrict__ counts,
                                               const int* __restrict__ col,
                                               const float* __restrict__ bl1) {
    int node = blockIdx.x * 4 + (threadIdx.x >> 6);
    int lane = threadIdx.x & 63;
    if (node >= NN) return;
    int e0 = rowp[node], cnt = counts[node];
    float ax = 0.f, ay = 0.f;
    const float2* T = (const float2*)t1;
    for (int base = 0; base < cnt; base += 64) {
        int m = cnt - base; if (m > 64) m = 64;
        int myS = (base + lane < cnt) ? col[e0 + base + lane] : 0;
        for (int i = 0; i < m; ++i) {
            int s = __shfl(myS, i);
            float2 v = T[(size_t)s * 64 + lane];
            ax += v.x; ay += v.y;
        }
    }
    float di = (cnt > 0) ? 1.0f / (float)cnt : 0.0f;
    float2 rr = ((const float2*)r1)[(size_t)node * 64 + lane];
    float2 bb = ((const float2*)bl1)[lane];
    float2 h;
    h.x = fmaxf(fmaf(ax, di, bb.x + rr.x), 0.0f);
    h.y = fmaxf(fmaf(ay, di, bb.y + rr.y), 0.0f);
    ((float2*)r1)[(size_t)node * 64 + lane] = h;
}

// ------- Aggregation 2 + L2 normalize: out = normalize(mean(t2[src]) + bl2 + r2)

__global__ __launch_bounds__(256) void k_aggr2(const float* __restrict__ t2,
                                               const float* __restrict__ r2,
                                               const int* __restrict__ rowp,
                                               const int* __restrict__ counts,
                                               const int* __restrict__ col,
                                               const float* __restrict__ bl2,
                                               float* __restrict__ out) {
    int node = blockIdx.x * 4 + (threadIdx.x >> 6);
    int lane = threadIdx.x & 63;
    if (node >= NN) return;
    int e0 = rowp[node], cnt = counts[node];
    float acc = 0.f;
    for (int base = 0; base < cnt; base += 64) {
        int m = cnt - base; if (m > 64) m = 64;
        int myS = (base + lane < cnt) ? col[e0 + base + lane] : 0;
        for (int i = 0; i < m; ++i) {
            int s = __shfl(myS, i);
            acc += t2[(size_t)s * 64 + lane];
        }
    }
    float di = (cnt > 0) ? 1.0f / (float)cnt : 0.0f;
    float v = fmaf(acc, di, bl2[lane] + r2[(size_t)node * 64 + lane]);
    float ss = v * v;
#pragma unroll
    for (int off = 32; off > 0; off >>= 1) ss += __shfl_xor(ss, off);
    float nrm = sqrtf(ss);
    out[(size_t)node * 64 + lane] = v / fmaxf(nrm, 1e-12f);
}

// ---------------- launch ----------------

extern "C" void kernel_launch(void* const* d_in, const int* in_sizes, int n_in,
                              void* d_out, int out_size, void* d_ws, size_t ws_size,
                              hipStream_t stream) {
    const float* x    = (const float*)d_in[0];
    const int*   ei   = (const int*)d_in[1];
    const float* Wpre = (const float*)d_in[2];
    const float* bpre = (const float*)d_in[3];
    const float* Wl1  = (const float*)d_in[4];
    const float* bl1  = (const float*)d_in[5];
    const float* Wr1  = (const float*)d_in[6];
    const float* Wl2  = (const float*)d_in[7];
    const float* bl2  = (const float*)d_in[8];
    const float* Wr2  = (const float*)d_in[9];
    float* out = (float*)d_out;

    char* w = (char*)d_ws;
    int* counts = (int*)w;  w += (size_t)NN * 4;
    int* cursor = (int*)w;  w += (size_t)NN * 4;
    int* rowp   = (int*)w;  w += (size_t)NN * 4;
    int* bsums  = (int*)w;  w += 256;
    int* col    = (int*)w;  w += (size_t)EE * 4;
    float* t1   = (float*)w; w += (size_t)NN * 128 * 4;   // h0 -> t1 in-place
    float* r1   = (float*)w; w += (size_t)NN * 128 * 4;   // r1 -> h1 in-place
    float* t2   = (float*)w; w += (size_t)NN * 64 * 4;
    float* r2   = (float*)w; w += (size_t)NN * 64 * 4;
    // packed transposed bf16 weights (hi/lo)
    short* WpH  = (short*)w; w += (size_t)256 * 128 * 2;
    short* WpL  = (short*)w; w += (size_t)256 * 128 * 2;
    short* W1lH = (short*)w; w += (size_t)128 * 128 * 2;
    short* W1lL = (short*)w; w += (size_t)128 * 128 * 2;
    short* W1rH = (short*)w; w += (size_t)128 * 128 * 2;
    short* W1rL = (short*)w; w += (size_t)128 * 128 * 2;
    short* W2lH = (short*)w; w += (size_t)128 * 64 * 2;
    short* W2lL = (short*)w; w += (size_t)128 * 64 * 2;
    short* W2rH = (short*)w; w += (size_t)128 * 64 * 2;
    short* W2rL = (short*)w; w += (size_t)128 * 64 * 2;

    hipMemsetAsync(counts, 0, (size_t)NN * 8, stream);    // counts + cursor

    dim3 b256(256);
    dim3 gE((EE + 255) / 256);
    k_count<<<gE, b256, 0, stream>>>(ei, counts);
    k_scan_a<<<dim3(NBLK), b256, 0, stream>>>(counts, bsums);
    k_scan_b<<<dim3(1), dim3(64), 0, stream>>>(bsums);
    k_scan_c<<<dim3(NBLK), b256, 0, stream>>>(counts, bsums, rowp);
    k_scatter<<<gE, b256, 0, stream>>>(ei, rowp, cursor, col);

    k_pack<<<dim3(128), b256, 0, stream>>>(Wpre, WpH, WpL, 256, 128);
    k_pack<<<dim3(64),  b256, 0, stream>>>(Wl1, W1lH, W1lL, 128, 128);
    k_pack<<<dim3(64),  b256, 0, stream>>>(Wr1, W1rH, W1rL, 128, 128);
    k_pack<<<dim3(32),  b256, 0, stream>>>(Wl2, W2lH, W2lL, 128, 64);
    k_pack<<<dim3(32),  b256, 0, stream>>>(Wr2, W2rH, W2rL, 128, 64);

    dim3 gG((NN + 63) / 64);
    k_gemm_pre<<<gG, b256, 0, stream>>>(x, WpH, WpL, bpre, t1);               // h0
    k_gemm_dual<128><<<gG, b256, 0, stream>>>(t1, W1lH, W1lL, W1rH, W1rL, t1, r1);
    k_aggr1<<<dim3((NN + 3) / 4), b256, 0, stream>>>(t1, r1, rowp, counts, col, bl1);
    k_gemm_dual<64><<<gG, b256, 0, stream>>>(r1, W2lH, W2lL, W2rH, W2rL, t2, r2);
    k_aggr2<<<dim3((NN + 3) / 4), b256, 0, stream>>>(t2, r2, rowp, counts, col, bl2, out);
}

// Round 3
// 377.985 us; speedup vs baseline: 1.2036x; 1.2036x over previous
//
#include <hip/hip_runtime.h>

// GraphSAGE 2-layer pipeline. MFMA bf16 3-term split GEMMs with
// register-resident B (persistent waves, LDS-free, barrier-free).
// N=50000 (divisible by 16), E=600000, edge_index int32.

#define NN   50000
#define EE   600000
#define NBLK 49          // ceil(NN/1024)
#define NRG  1563        // ceil(NN/32) row-groups of 32 rows
#define GEMM_BLOCKS 512  // 2048 persistent waves (~2/SIMD at ~200 VGPR)

typedef __attribute__((ext_vector_type(8))) short short8v;   // 8 x bf16
typedef __attribute__((ext_vector_type(4))) short short4v;
typedef __attribute__((ext_vector_type(2))) short short2v;
typedef __attribute__((ext_vector_type(4))) float f32x4;

__device__ inline short bf_trunc(float f) {
    return (short)(__builtin_bit_cast(unsigned, f) >> 16);
}
__device__ inline short bf_rne(float f) {
    unsigned u = __builtin_bit_cast(unsigned, f);
    unsigned r = u + 0x7FFFu + ((u >> 16) & 1u);
    return (short)(r >> 16);
}
__device__ inline float bf_to_f(short h) {
    return __builtin_bit_cast(float, ((unsigned)(unsigned short)h) << 16);
}

// ---------------- CSR build ----------------

__global__ __launch_bounds__(256) void k_count(const int* __restrict__ ei,
                                               int* __restrict__ counts) {
    int e = blockIdx.x * 256 + threadIdx.x;
    if (e < EE) atomicAdd(&counts[ei[EE + e]], 1);
}

__global__ __launch_bounds__(256) void k_scan_a(const int* __restrict__ counts,
                                                int* __restrict__ bsums) {
    int b = blockIdx.x, t = threadIdx.x;
    int idx = b * 1024 + t * 4;
    int s = 0;
#pragma unroll
    for (int j = 0; j < 4; ++j)
        if (idx + j < NN) s += counts[idx + j];
#pragma unroll
    for (int off = 32; off > 0; off >>= 1) s += __shfl_down(s, off);
    __shared__ int ls[4];
    if ((t & 63) == 0) ls[t >> 6] = s;
    __syncthreads();
    if (t == 0) bsums[b] = ls[0] + ls[1] + ls[2] + ls[3];
}

__global__ void k_scan_b(int* __restrict__ bsums) {
    int t = threadIdx.x;                       // 64 threads
    int v = (t < NBLK) ? bsums[t] : 0;
    int orig = v;
#pragma unroll
    for (int off = 1; off < 64; off <<= 1) {
        int u = __shfl_up(v, off);
        if (t >= off) v += u;
    }
    if (t < NBLK) bsums[t] = v - orig;          // exclusive
}

__global__ __launch_bounds__(256) void k_scan_c(const int* __restrict__ counts,
                                                const int* __restrict__ bsums,
                                                int* __restrict__ rowp) {
    int b = blockIdx.x, t = threadIdx.x;
    int lane = t & 63, wave = t >> 6;
    int idx = b * 1024 + t * 4;
    int c[4], s = 0;
#pragma unroll
    for (int j = 0; j < 4; ++j) {
        c[j] = (idx + j < NN) ? counts[idx + j] : 0;
        s += c[j];
    }
    int sv = s;
#pragma unroll
    for (int off = 1; off < 64; off <<= 1) {
        int u = __shfl_up(sv, off);
        if (lane >= off) sv += u;
    }
    __shared__ int lsum[4];
    if (lane == 63) lsum[wave] = sv;
    __syncthreads();
    int woff = 0;
    for (int wv = 0; wv < wave; ++wv) woff += lsum[wv];
    int base = bsums[b] + woff + (sv - s);
#pragma unroll
    for (int j = 0; j < 4; ++j) {
        if (idx + j < NN) { rowp[idx + j] = base; base += c[j]; }
    }
}

__global__ __launch_bounds__(256) void k_scatter(const int* __restrict__ ei,
                                                 const int* __restrict__ rowp,
                                                 int* __restrict__ cursor,
                                                 int* __restrict__ col) {
    int e = blockIdx.x * 256 + threadIdx.x;
    if (e < EE) {
        int d = ei[EE + e];
        int p = atomicAdd(&cursor[d], 1);
        col[rowp[d] + p] = ei[e];
    }
}

// --------- split fp32 -> bf16 hi (trunc) + lo (rne of residual), vectorized ---

__global__ __launch_bounds__(256) void k_split(const float* __restrict__ in,
                                               short* __restrict__ hi,
                                               short* __restrict__ lo, int n4) {
    int i = blockIdx.x * 256 + threadIdx.x;
    if (i >= n4) return;
    float4 v = ((const float4*)in)[i];
    float a[4] = {v.x, v.y, v.z, v.w};
    short4v h, l;
#pragma unroll
    for (int j = 0; j < 4; ++j) {
        h[j] = bf_trunc(a[j]);
        l[j] = bf_rne(a[j] - bf_to_f(h[j]));
    }
    ((short4v*)hi)[i] = h;
    ((short4v*)lo)[i] = l;
}

// ---------------- weight pack: W[K][M] fp32 -> Wt_hi/Wt_lo [M][K] bf16 --------

__global__ __launch_bounds__(256) void k_pack(const float* __restrict__ W,
                                              short* __restrict__ hi,
                                              short* __restrict__ lo,
                                              int K, int M) {
    int idx = blockIdx.x * 256 + threadIdx.x;
    if (idx >= K * M) return;
    int k = idx / M, m = idx - k * M;
    float w = W[idx];
    short h = bf_rne(w);
    hi[m * K + k] = h;
    lo[m * K + k] = bf_rne(w - bf_to_f(h));
}

// ---------------- GEMM pre: h0 = x @ W_pre + b_pre  (K=256, M=128) ------------
// Wave: 32-col slice (cs of 4), persistent over 32-row groups. B in registers.

__global__ __launch_bounds__(256, 2) void k_gemm_pre(
        const short* __restrict__ xhi, const short* __restrict__ xlo,
        const short* __restrict__ WH,  const short* __restrict__ WL,
        const float* __restrict__ bp,
        short* __restrict__ h0hi, short* __restrict__ h0lo) {
    const int wave = threadIdx.x >> 6, lane = threadIdx.x & 63;
    const int r = lane & 15, kb = lane >> 4;
    const int gw = blockIdx.x * 4 + wave;
    const int cs = gw & 3;
    const int col0 = cs << 5;

    short8v bh[2][8], bl[2][8];
#pragma unroll
    for (int nt = 0; nt < 2; ++nt)
#pragma unroll
        for (int k = 0; k < 8; ++k) {
            size_t off = (size_t)(col0 + nt * 16 + r) * 256 + k * 32 + kb * 8;
            bh[nt][k] = *(const short8v*)&WH[off];
            bl[nt][k] = *(const short8v*)&WL[off];
        }
    float bias[2];
#pragma unroll
    for (int nt = 0; nt < 2; ++nt) bias[nt] = bp[col0 + nt * 16 + r];

    const int stride = (gridDim.x * 4) >> 2;
    for (int rg = gw >> 2; rg < NRG; rg += stride) {
        const int row0 = rg << 5;
        f32x4 acc[2][2];
#pragma unroll
        for (int a = 0; a < 2; ++a)
#pragma unroll
            for (int b = 0; b < 2; ++b) acc[a][b] = (f32x4){0.f, 0.f, 0.f, 0.f};

#pragma unroll
        for (int k = 0; k < 8; ++k) {
            short8v ah[2], al[2];
#pragma unroll
            for (int rt = 0; rt < 2; ++rt) {
                int rr = row0 + rt * 16;            // tile-uniform validity
                if (rr < NN) {
                    size_t off = (size_t)(rr + r) * 256 + k * 32 + kb * 8;
                    ah[rt] = *(const short8v*)&xhi[off];
                    al[rt] = *(const short8v*)&xlo[off];
                } else {
                    ah[rt] = (short8v){0,0,0,0,0,0,0,0};
                    al[rt] = (short8v){0,0,0,0,0,0,0,0};
                }
            }
#pragma unroll
            for (int rt = 0; rt < 2; ++rt)
#pragma unroll
                for (int nt = 0; nt < 2; ++nt) {
                    acc[rt][nt] = __builtin_amdgcn_mfma_f32_16x16x32_bf16(ah[rt], bh[nt][k], acc[rt][nt], 0, 0, 0);
                    acc[rt][nt] = __builtin_amdgcn_mfma_f32_16x16x32_bf16(al[rt], bh[nt][k], acc[rt][nt], 0, 0, 0);
                    acc[rt][nt] = __builtin_amdgcn_mfma_f32_16x16x32_bf16(ah[rt], bl[nt][k], acc[rt][nt], 0, 0, 0);
                }
        }
#pragma unroll
        for (int rt = 0; rt < 2; ++rt) {
            if (row0 + rt * 16 >= NN) continue;
            int rbase = row0 + rt * 16 + kb * 4;
#pragma unroll
            for (int nt = 0; nt < 2; ++nt) {
                int c = col0 + nt * 16 + r;
#pragma unroll
                for (int j = 0; j < 4; ++j) {
                    float v = acc[rt][nt][j] + bias[nt];
                    short h = bf_trunc(v);
                    size_t o = (size_t)(rbase + j) * 128 + c;
                    h0hi[o] = h;
                    h0lo[o] = bf_rne(v - bf_to_f(h));
                }
            }
        }
    }
}

// ------- Dual GEMM: T = A@W1, R = A@W2 (K=128, M in {128,64}), fp32 out -------

template <int M>
__global__ __launch_bounds__(256, 2) void k_gemm_dual(
        const short* __restrict__ Ahi, const short* __restrict__ Alo,
        const short* __restrict__ W1H, const short* __restrict__ W1L,
        const short* __restrict__ W2H, const short* __restrict__ W2L,
        float* __restrict__ T, float* __restrict__ R) {
    constexpr int CS = M / 32;          // col slices
    const int wave = threadIdx.x >> 6, lane = threadIdx.x & 63;
    const int r = lane & 15, kb = lane >> 4;
    const int gw = blockIdx.x * 4 + wave;
    const int cs = gw % CS;
    const int col0 = cs << 5;

    short8v b1h[2][4], b1l[2][4], b2h[2][4], b2l[2][4];
#pragma unroll
    for (int nt = 0; nt < 2; ++nt)
#pragma unroll
        for (int k = 0; k < 4; ++k) {
            size_t off = (size_t)(col0 + nt * 16 + r) * 128 + k * 32 + kb * 8;
            b1h[nt][k] = *(const short8v*)&W1H[off];
            b1l[nt][k] = *(const short8v*)&W1L[off];
            b2h[nt][k] = *(const short8v*)&W2H[off];
            b2l[nt][k] = *(const short8v*)&W2L[off];
        }

    const int stride = (gridDim.x * 4) / CS;
    for (int rg = gw / CS; rg < NRG; rg += stride) {
        const int row0 = rg << 5;
        f32x4 accT[2][2], accR[2][2];
#pragma unroll
        for (int a = 0; a < 2; ++a)
#pragma unroll
            for (int b = 0; b < 2; ++b) {
                accT[a][b] = (f32x4){0.f, 0.f, 0.f, 0.f};
                accR[a][b] = (f32x4){0.f, 0.f, 0.f, 0.f};
            }
#pragma unroll
        for (int k = 0; k < 4; ++k) {
            short8v ah[2], al[2];
#pragma unroll
            for (int rt = 0; rt < 2; ++rt) {
                int rr = row0 + rt * 16;
                if (rr < NN) {
                    size_t off = (size_t)(rr + r) * 128 + k * 32 + kb * 8;
                    ah[rt] = *(const short8v*)&Ahi[off];
                    al[rt] = *(const short8v*)&Alo[off];
                } else {
                    ah[rt] = (short8v){0,0,0,0,0,0,0,0};
                    al[rt] = (short8v){0,0,0,0,0,0,0,0};
                }
            }
#pragma unroll
            for (int rt = 0; rt < 2; ++rt)
#pragma unroll
                for (int nt = 0; nt < 2; ++nt) {
                    accT[rt][nt] = __builtin_amdgcn_mfma_f32_16x16x32_bf16(ah[rt], b1h[nt][k], accT[rt][nt], 0, 0, 0);
                    accT[rt][nt] = __builtin_amdgcn_mfma_f32_16x16x32_bf16(al[rt], b1h[nt][k], accT[rt][nt], 0, 0, 0);
                    accT[rt][nt] = __builtin_amdgcn_mfma_f32_16x16x32_bf16(ah[rt], b1l[nt][k], accT[rt][nt], 0, 0, 0);
                    accR[rt][nt] = __builtin_amdgcn_mfma_f32_16x16x32_bf16(ah[rt], b2h[nt][k], accR[rt][nt], 0, 0, 0);
                    accR[rt][nt] = __builtin_amdgcn_mfma_f32_16x16x32_bf16(al[rt], b2h[nt][k], accR[rt][nt], 0, 0, 0);
                    accR[rt][nt] = __builtin_amdgcn_mfma_f32_16x16x32_bf16(ah[rt], b2l[nt][k], accR[rt][nt], 0, 0, 0);
                }
        }
#pragma unroll
        for (int rt = 0; rt < 2; ++rt) {
            if (row0 + rt * 16 >= NN) continue;
            int rbase = row0 + rt * 16 + kb * 4;
#pragma unroll
            for (int nt = 0; nt < 2; ++nt) {
                int c = col0 + nt * 16 + r;
#pragma unroll
                for (int j = 0; j < 4; ++j) {
                    T[(size_t)(rbase + j) * M + c] = accT[rt][nt][j];
                    R[(size_t)(rbase + j) * M + c] = accR[rt][nt][j];
                }
            }
        }
    }
}

// ------- Aggregation 1: h1 = relu(mean(t1[src]) + bl1 + r1) -> bf16 hi/lo -----

__global__ __launch_bounds__(256) void k_aggr1(const float* __restrict__ t1,
                                               const float* __restrict__ r1,
                                               const int* __restrict__ rowp,
                                               const int* __restrict__ counts,
                                               const int* __restrict__ col,
                                               const float* __restrict__ bl1,
                                               short* __restrict__ h1hi,
                                               short* __restrict__ h1lo) {
    int node = blockIdx.x * 4 + (threadIdx.x >> 6);
    int lane = threadIdx.x & 63;
    if (node >= NN) return;
    int e0 = rowp[node], cnt = counts[node];
    float ax = 0.f, ay = 0.f;
    const float2* T = (const float2*)t1;
    for (int base = 0; base < cnt; base += 64) {
        int m = cnt - base; if (m > 64) m = 64;
        int myS = (base + lane < cnt) ? col[e0 + base + lane] : 0;
        for (int i = 0; i < m; ++i) {
            int s = __shfl(myS, i);
            float2 v = T[(size_t)s * 64 + lane];
            ax += v.x; ay += v.y;
        }
    }
    float di = (cnt > 0) ? 1.0f / (float)cnt : 0.0f;
    float2 rr = ((const float2*)r1)[(size_t)node * 64 + lane];
    float2 bb = ((const float2*)bl1)[lane];
    float hx = fmaxf(fmaf(ax, di, bb.x + rr.x), 0.0f);
    float hy = fmaxf(fmaf(ay, di, bb.y + rr.y), 0.0f);
    short2v h, l;
    h[0] = bf_trunc(hx); l[0] = bf_rne(hx - bf_to_f(h[0]));
    h[1] = bf_trunc(hy); l[1] = bf_rne(hy - bf_to_f(h[1]));
    ((short2v*)h1hi)[(size_t)node * 64 + lane] = h;
    ((short2v*)h1lo)[(size_t)node * 64 + lane] = l;
}

// ------- Aggregation 2 + L2 normalize ----------------------------------------

__global__ __launch_bounds__(256) void k_aggr2(const float* __restrict__ t2,
                                               const float* __restrict__ r2,
                                               const int* __restrict__ rowp,
                                               const int* __restrict__ counts,
                                               const int* __restrict__ col,
                                               const float* __restrict__ bl2,
                                               float* __restrict__ out) {
    int node = blockIdx.x * 4 + (threadIdx.x >> 6);
    int lane = threadIdx.x & 63;
    if (node >= NN) return;
    int e0 = rowp[node], cnt = counts[node];
    float acc = 0.f;
    for (int base = 0; base < cnt; base += 64) {
        int m = cnt - base; if (m > 64) m = 64;
        int myS = (base + lane < cnt) ? col[e0 + base + lane] : 0;
        for (int i = 0; i < m; ++i) {
            int s = __shfl(myS, i);
            acc += t2[(size_t)s * 64 + lane];
        }
    }
    float di = (cnt > 0) ? 1.0f / (float)cnt : 0.0f;
    float v = fmaf(acc, di, bl2[lane] + r2[(size_t)node * 64 + lane]);
    float ss = v * v;
#pragma unroll
    for (int off = 32; off > 0; off >>= 1) ss += __shfl_xor(ss, off);
    float nrm = sqrtf(ss);
    out[(size_t)node * 64 + lane] = v / fmaxf(nrm, 1e-12f);
}

// ---------------- launch ----------------

extern "C" void kernel_launch(void* const* d_in, const int* in_sizes, int n_in,
                              void* d_out, int out_size, void* d_ws, size_t ws_size,
                              hipStream_t stream) {
    const float* x    = (const float*)d_in[0];
    const int*   ei   = (const int*)d_in[1];
    const float* Wpre = (const float*)d_in[2];
    const float* bpre = (const float*)d_in[3];
    const float* Wl1  = (const float*)d_in[4];
    const float* bl1  = (const float*)d_in[5];
    const float* Wr1  = (const float*)d_in[6];
    const float* Wl2  = (const float*)d_in[7];
    const float* bl2  = (const float*)d_in[8];
    const float* Wr2  = (const float*)d_in[9];
    float* out = (float*)d_out;

    char* w = (char*)d_ws;
    int* counts = (int*)w;  w += (size_t)NN * 4;
    int* cursor = (int*)w;  w += (size_t)NN * 4;
    int* rowp   = (int*)w;  w += (size_t)NN * 4;
    int* bsums  = (int*)w;  w += 256;
    int* col    = (int*)w;  w += (size_t)EE * 4;
    // packed transposed bf16 weights (hi/lo)
    short* WpH  = (short*)w; w += (size_t)256 * 128 * 2;
    short* WpL  = (short*)w; w += (size_t)256 * 128 * 2;
    short* W1lH = (short*)w; w += (size_t)128 * 128 * 2;
    short* W1lL = (short*)w; w += (size_t)128 * 128 * 2;
    short* W1rH = (short*)w; w += (size_t)128 * 128 * 2;
    short* W1rL = (short*)w; w += (size_t)128 * 128 * 2;
    short* W2lH = (short*)w; w += (size_t)128 * 64 * 2;
    short* W2lL = (short*)w; w += (size_t)128 * 64 * 2;
    short* W2rH = (short*)w; w += (size_t)128 * 64 * 2;
    short* W2rL = (short*)w; w += (size_t)128 * 64 * 2;
    // region X: xhi|xlo (25.6MB each); later t1 (fp32) at xhi, r1 (fp32) at xlo
    short* xhi  = (short*)w;
    float* t1   = (float*)w; w += (size_t)NN * 256 * 2;
    short* xlo  = (short*)w;
    float* r1   = (float*)w; w += (size_t)NN * 256 * 2;
    // region H0: h0hi|h0lo (12.8MB each); later t2 (fp32) at h0hi, r2 at h0lo
    short* h0hi = (short*)w;
    float* t2   = (float*)w; w += (size_t)NN * 128 * 2;
    short* h0lo = (short*)w;
    float* r2   = (float*)w; w += (size_t)NN * 128 * 2;
    // h1 hi/lo
    short* h1hi = (short*)w; w += (size_t)NN * 128 * 2;
    short* h1lo = (short*)w; w += (size_t)NN * 128 * 2;

    hipMemsetAsync(counts, 0, (size_t)NN * 8, stream);    // counts + cursor

    dim3 b256(256);
    dim3 gE((EE + 255) / 256);
    k_count<<<gE, b256, 0, stream>>>(ei, counts);
    k_scan_a<<<dim3(NBLK), b256, 0, stream>>>(counts, bsums);
    k_scan_b<<<dim3(1), dim3(64), 0, stream>>>(bsums);
    k_scan_c<<<dim3(NBLK), b256, 0, stream>>>(counts, bsums, rowp);
    k_scatter<<<gE, b256, 0, stream>>>(ei, rowp, cursor, col);

    k_split<<<dim3((NN * 256 / 4 + 255) / 256), b256, 0, stream>>>(x, xhi, xlo, NN * 256 / 4);
    k_pack<<<dim3(128), b256, 0, stream>>>(Wpre, WpH, WpL, 256, 128);
    k_pack<<<dim3(64),  b256, 0, stream>>>(Wl1, W1lH, W1lL, 128, 128);
    k_pack<<<dim3(64),  b256, 0, stream>>>(Wr1, W1rH, W1rL, 128, 128);
    k_pack<<<dim3(32),  b256, 0, stream>>>(Wl2, W2lH, W2lL, 128, 64);
    k_pack<<<dim3(32),  b256, 0, stream>>>(Wr2, W2rH, W2rL, 128, 64);

    dim3 gP(GEMM_BLOCKS);
    k_gemm_pre<<<gP, b256, 0, stream>>>(xhi, xlo, WpH, WpL, bpre, h0hi, h0lo);
    k_gemm_dual<128><<<gP, b256, 0, stream>>>(h0hi, h0lo, W1lH, W1lL, W1rH, W1rL, t1, r1);
    k_aggr1<<<dim3((NN + 3) / 4), b256, 0, stream>>>(t1, r1, rowp, counts, col, bl1, h1hi, h1lo);
    k_gemm_dual<64><<<gP, b256, 0, stream>>>(h1hi, h1lo, W2lH, W2lL, W2rH, W2rL, t2, r2);
    k_aggr2<<<dim3((NN + 3) / 4), b256, 0, stream>>>(t2, r2, rowp, counts, col, bl2, out);
}

// Round 5
// 304.479 us; speedup vs baseline: 1.4942x; 1.2414x over previous
//
#include <hip/hip_runtime.h>

// GraphSAGE 2-layer pipeline, fp16 activations end-to-end.
// GEMMs: MFMA f16 (A single fp16, B fp16 hi+lo 2-term). fp32 accumulate.
// N=50000, E=600000, edge_index int32.

#define NN   50000
#define EE   600000
#define NBLK 49          // ceil(NN/1024)
#define NRG  1563        // ceil(NN/32) row-groups of 32 rows
#define GEMM_BLOCKS 512

typedef __attribute__((ext_vector_type(8))) _Float16 h8v;
typedef __attribute__((ext_vector_type(4))) _Float16 h4v;
typedef __attribute__((ext_vector_type(2))) _Float16 h2v;
typedef __attribute__((ext_vector_type(8))) short short8v;
typedef __attribute__((ext_vector_type(4))) float f32x4;

__device__ inline h8v h8zero() {
    return __builtin_bit_cast(h8v, (short8v){0,0,0,0,0,0,0,0});
}

// ---------------- CSR build ----------------

__global__ __launch_bounds__(256) void k_count(const int* __restrict__ ei,
                                               int* __restrict__ counts) {
    int e = blockIdx.x * 256 + threadIdx.x;
    if (e < EE) atomicAdd(&counts[ei[EE + e]], 1);
}

__global__ __launch_bounds__(256) void k_scan_a(const int* __restrict__ counts,
                                                int* __restrict__ bsums) {
    int b = blockIdx.x, t = threadIdx.x;
    int idx = b * 1024 + t * 4;
    int s = 0;
#pragma unroll
    for (int j = 0; j < 4; ++j)
        if (idx + j < NN) s += counts[idx + j];
#pragma unroll
    for (int off = 32; off > 0; off >>= 1) s += __shfl_down(s, off);
    __shared__ int ls[4];
    if ((t & 63) == 0) ls[t >> 6] = s;
    __syncthreads();
    if (t == 0) bsums[b] = ls[0] + ls[1] + ls[2] + ls[3];
}

__global__ void k_scan_b(int* __restrict__ bsums) {
    int t = threadIdx.x;                       // 64 threads
    int v = (t < NBLK) ? bsums[t] : 0;
    int orig = v;
#pragma unroll
    for (int off = 1; off < 64; off <<= 1) {
        int u = __shfl_up(v, off);
        if (t >= off) v += u;
    }
    if (t < NBLK) bsums[t] = v - orig;          // exclusive
}

__global__ __launch_bounds__(256) void k_scan_c(const int* __restrict__ counts,
                                                const int* __restrict__ bsums,
                                                int* __restrict__ rowp) {
    int b = blockIdx.x, t = threadIdx.x;
    int lane = t & 63, wave = t >> 6;
    int idx = b * 1024 + t * 4;
    int c[4], s = 0;
#pragma unroll
    for (int j = 0; j < 4; ++j) {
        c[j] = (idx + j < NN) ? counts[idx + j] : 0;
        s += c[j];
    }
    int sv = s;
#pragma unroll
    for (int off = 1; off < 64; off <<= 1) {
        int u = __shfl_up(sv, off);
        if (lane >= off) sv += u;
    }
    __shared__ int lsum[4];
    if (lane == 63) lsum[wave] = sv;
    __syncthreads();
    int woff = 0;
    for (int wv = 0; wv < wave; ++wv) woff += lsum[wv];
    int base = bsums[b] + woff + (sv - s);
#pragma unroll
    for (int j = 0; j < 4; ++j) {
        if (idx + j < NN) { rowp[idx + j] = base; base += c[j]; }
    }
}

__global__ __launch_bounds__(256) void k_scatter(const int* __restrict__ ei,
                                                 const int* __restrict__ rowp,
                                                 int* __restrict__ cursor,
                                                 int* __restrict__ col) {
    int e = blockIdx.x * 256 + threadIdx.x;
    if (e < EE) {
        int d = ei[EE + e];
        int p = atomicAdd(&cursor[d], 1);
        col[rowp[d] + p] = ei[e];
    }
}

// ---------------- x: fp32 -> fp16 ----------------

__global__ __launch_bounds__(256) void k_cvt(const float* __restrict__ in,
                                             _Float16* __restrict__ outp, int n4) {
    int i = blockIdx.x * 256 + threadIdx.x;
    if (i >= n4) return;
    float4 v = ((const float4*)in)[i];
    h4v o;
    o[0] = (_Float16)v.x; o[1] = (_Float16)v.y;
    o[2] = (_Float16)v.z; o[3] = (_Float16)v.w;
    ((h4v*)outp)[i] = o;
}

// -------- weight pack: W[K][M] fp32 -> Wt hi/lo fp16 [M][K] -------------------

__global__ __launch_bounds__(256) void k_pack(const float* __restrict__ W,
                                              _Float16* __restrict__ hi,
                                              _Float16* __restrict__ lo,
                                              int K, int M) {
    int idx = blockIdx.x * 256 + threadIdx.x;
    if (idx >= K * M) return;
    int k = idx / M, m = idx - k * M;
    float w = W[idx];
    _Float16 h = (_Float16)w;
    hi[m * K + k] = h;
    lo[m * K + k] = (_Float16)(w - (float)h);
}

// ---------------- GEMM pre: h0 = fp16(x @ W_pre + b_pre)  (K=256, M=128) ------
// Wave: 32-col slice, persistent over 32-row groups. B (hi+lo) in registers.

__global__ __launch_bounds__(256, 2) void k_gemm_pre(
        const _Float16* __restrict__ xh,
        const _Float16* __restrict__ WH, const _Float16* __restrict__ WL,
        const float* __restrict__ bp, _Float16* __restrict__ h0) {
    const int wave = threadIdx.x >> 6, lane = threadIdx.x & 63;
    const int r = lane & 15, kb = lane >> 4;
    const int gw = blockIdx.x * 4 + wave;
    const int col0 = (gw & 3) << 5;

    h8v bh[2][8], bl[2][8];
#pragma unroll
    for (int nt = 0; nt < 2; ++nt)
#pragma unroll
        for (int k = 0; k < 8; ++k) {
            size_t off = (size_t)(col0 + nt * 16 + r) * 256 + k * 32 + kb * 8;
            bh[nt][k] = *(const h8v*)&WH[off];
            bl[nt][k] = *(const h8v*)&WL[off];
        }
    float bias[2];
#pragma unroll
    for (int nt = 0; nt < 2; ++nt) bias[nt] = bp[col0 + nt * 16 + r];

    for (int rg = gw >> 2; rg < NRG; rg += GEMM_BLOCKS) {
        const int row0 = rg << 5;
        f32x4 acc[2][2];
#pragma unroll
        for (int a = 0; a < 2; ++a)
#pragma unroll
            for (int b = 0; b < 2; ++b) acc[a][b] = (f32x4){0.f, 0.f, 0.f, 0.f};

#pragma unroll
        for (int k = 0; k < 8; ++k) {
            h8v ah[2];
#pragma unroll
            for (int rt = 0; rt < 2; ++rt) {
                int rr = row0 + rt * 16;
                ah[rt] = (rr < NN) ? *(const h8v*)&xh[(size_t)(rr + r) * 256 + k * 32 + kb * 8]
                                   : h8zero();
            }
#pragma unroll
            for (int rt = 0; rt < 2; ++rt)
#pragma unroll
                for (int nt = 0; nt < 2; ++nt) {
                    acc[rt][nt] = __builtin_amdgcn_mfma_f32_16x16x32_f16(ah[rt], bh[nt][k], acc[rt][nt], 0, 0, 0);
                    acc[rt][nt] = __builtin_amdgcn_mfma_f32_16x16x32_f16(ah[rt], bl[nt][k], acc[rt][nt], 0, 0, 0);
                }
        }
#pragma unroll
        for (int rt = 0; rt < 2; ++rt) {
            if (row0 + rt * 16 >= NN) continue;
            int rbase = row0 + rt * 16 + kb * 4;
#pragma unroll
            for (int nt = 0; nt < 2; ++nt) {
                int c = col0 + nt * 16 + r;
#pragma unroll
                for (int j = 0; j < 4; ++j)
                    h0[(size_t)(rbase + j) * 128 + c] = (_Float16)(acc[rt][nt][j] + bias[nt]);
            }
        }
    }
}

// ------- Dual GEMM: T = A@W1, R = A@W2 (K=128, M in {128,64}), fp16 out -------

template <int M>
__global__ __launch_bounds__(256, 2) void k_gemm_dual(
        const _Float16* __restrict__ A,
        const _Float16* __restrict__ W1H, const _Float16* __restrict__ W1L,
        const _Float16* __restrict__ W2H, const _Float16* __restrict__ W2L,
        _Float16* __restrict__ T, _Float16* __restrict__ R) {
    constexpr int CS = M / 32;
    const int wave = threadIdx.x >> 6, lane = threadIdx.x & 63;
    const int r = lane & 15, kb = lane >> 4;
    const int gw = blockIdx.x * 4 + wave;
    const int col0 = (gw % CS) << 5;

    h8v b1h[2][4], b1l[2][4], b2h[2][4], b2l[2][4];
#pragma unroll
    for (int nt = 0; nt < 2; ++nt)
#pragma unroll
        for (int k = 0; k < 4; ++k) {
            size_t off = (size_t)(col0 + nt * 16 + r) * 128 + k * 32 + kb * 8;
            b1h[nt][k] = *(const h8v*)&W1H[off];
            b1l[nt][k] = *(const h8v*)&W1L[off];
            b2h[nt][k] = *(const h8v*)&W2H[off];
            b2l[nt][k] = *(const h8v*)&W2L[off];
        }

    const int stride = (GEMM_BLOCKS * 4) / CS;
    for (int rg = gw / CS; rg < NRG; rg += stride) {
        const int row0 = rg << 5;
        f32x4 accT[2][2], accR[2][2];
#pragma unroll
        for (int a = 0; a < 2; ++a)
#pragma unroll
            for (int b = 0; b < 2; ++b) {
                accT[a][b] = (f32x4){0.f, 0.f, 0.f, 0.f};
                accR[a][b] = (f32x4){0.f, 0.f, 0.f, 0.f};
            }
#pragma unroll
        for (int k = 0; k < 4; ++k) {
            h8v ah[2];
#pragma unroll
            for (int rt = 0; rt < 2; ++rt) {
                int rr = row0 + rt * 16;
                ah[rt] = (rr < NN) ? *(const h8v*)&A[(size_t)(rr + r) * 128 + k * 32 + kb * 8]
                                   : h8zero();
            }
#pragma unroll
            for (int rt = 0; rt < 2; ++rt)
#pragma unroll
                for (int nt = 0; nt < 2; ++nt) {
                    accT[rt][nt] = __builtin_amdgcn_mfma_f32_16x16x32_f16(ah[rt], b1h[nt][k], accT[rt][nt], 0, 0, 0);
                    accT[rt][nt] = __builtin_amdgcn_mfma_f32_16x16x32_f16(ah[rt], b1l[nt][k], accT[rt][nt], 0, 0, 0);
                    accR[rt][nt] = __builtin_amdgcn_mfma_f32_16x16x32_f16(ah[rt], b2h[nt][k], accR[rt][nt], 0, 0, 0);
                    accR[rt][nt] = __builtin_amdgcn_mfma_f32_16x16x32_f16(ah[rt], b2l[nt][k], accR[rt][nt], 0, 0, 0);
                }
        }
#pragma unroll
        for (int rt = 0; rt < 2; ++rt) {
            if (row0 + rt * 16 >= NN) continue;
            int rbase = row0 + rt * 16 + kb * 4;
#pragma unroll
            for (int nt = 0; nt < 2; ++nt) {
                int c = col0 + nt * 16 + r;
#pragma unroll
                for (int j = 0; j < 4; ++j) {
                    T[(size_t)(rbase + j) * M + c] = (_Float16)accT[rt][nt][j];
                    R[(size_t)(rbase + j) * M + c] = (_Float16)accR[rt][nt][j];
                }
            }
        }
    }
}

// ------- Aggregation 1: h1 = fp16(relu(mean(t1[src]) + bl1 + r1)) -------------
// one wave per node; lane holds dims (2*lane, 2*lane+1); 8-deep load batching.

__global__ __launch_bounds__(256) void k_aggr1(const _Float16* __restrict__ t1,
                                               const _Float16* __restrict__ r1,
                                               const int* __restrict__ rowp,
                                               const int* __restrict__ counts,
                                               const int* __restrict__ col,
                                               const float* __restrict__ bl1,
                                               _Float16* __restrict__ h1) {
    int node = blockIdx.x * 4 + (threadIdx.x >> 6);
    int lane = threadIdx.x & 63;
    if (node >= NN) return;
    int e0 = rowp[node], cnt = counts[node];
    float ax = 0.f, ay = 0.f;
    const h2v* T = (const h2v*)t1;
    for (int base = 0; base < cnt; base += 64) {
        int m = cnt - base; if (m > 64) m = 64;
        int myS = (base + lane < cnt) ? col[e0 + base + lane] : 0;
        int i = 0;
        for (; i + 8 <= m; i += 8) {
            int s0 = __shfl(myS, i + 0), s1 = __shfl(myS, i + 1);
            int s2 = __shfl(myS, i + 2), s3 = __shfl(myS, i + 3);
            int s4 = __shfl(myS, i + 4), s5 = __shfl(myS, i + 5);
            int s6 = __shfl(myS, i + 6), s7 = __shfl(myS, i + 7);
            h2v v0 = T[(size_t)s0 * 64 + lane], v1 = T[(size_t)s1 * 64 + lane];
            h2v v2 = T[(size_t)s2 * 64 + lane], v3 = T[(size_t)s3 * 64 + lane];
            h2v v4 = T[(size_t)s4 * 64 + lane], v5 = T[(size_t)s5 * 64 + lane];
            h2v v6 = T[(size_t)s6 * 64 + lane], v7 = T[(size_t)s7 * 64 + lane];
            ax += (float)v0[0] + (float)v1[0] + (float)v2[0] + (float)v3[0]
                + (float)v4[0] + (float)v5[0] + (float)v6[0] + (float)v7[0];
            ay += (float)v0[1] + (float)v1[1] + (float)v2[1] + (float)v3[1]
                + (float)v4[1] + (float)v5[1] + (float)v6[1] + (float)v7[1];
        }
        for (; i < m; ++i) {
            int s = __shfl(myS, i);
            h2v v = T[(size_t)s * 64 + lane];
            ax += (float)v[0]; ay += (float)v[1];
        }
    }
    float di = (cnt > 0) ? 1.0f / (float)cnt : 0.0f;
    h2v rr = ((const h2v*)r1)[(size_t)node * 64 + lane];
    float2 bb = ((const float2*)bl1)[lane];
    float hx = fmaxf(fmaf(ax, di, bb.x + (float)rr[0]), 0.0f);
    float hy = fmaxf(fmaf(ay, di, bb.y + (float)rr[1]), 0.0f);
    h2v h; h[0] = (_Float16)hx; h[1] = (_Float16)hy;
    ((h2v*)h1)[(size_t)node * 64 + lane] = h;
}

// ------- Aggregation 2 + L2 normalize -----------------------------------------
// one wave per node; two 32-lane halves process 2 neighbors per step.

__global__ __launch_bounds__(256) void k_aggr2(const _Float16* __restrict__ t2,
                                               const _Float16* __restrict__ r2,
                                               const int* __restrict__ rowp,
                                               const int* __restrict__ counts,
                                               const int* __restrict__ col,
                                               const float* __restrict__ bl2,
                                               float* __restrict__ out) {
    int node = blockIdx.x * 4 + (threadIdx.x >> 6);
    int lane = threadIdx.x & 63;
    if (node >= NN) return;
    int half = lane >> 5, sl = lane & 31;
    int e0 = rowp[node], cnt = counts[node];
    float ax = 0.f, ay = 0.f;
    const h2v* T = (const h2v*)t2;
    for (int base = 0; base < cnt; base += 64) {
        int m = cnt - base; if (m > 64) m = 64;
        int myS = (base + lane < cnt) ? col[e0 + base + lane] : 0;
        int i = 0;
        for (; i + 8 <= m; i += 8) {
            int s0 = __shfl(myS, i + 0 + half), s1 = __shfl(myS, i + 2 + half);
            int s2 = __shfl(myS, i + 4 + half), s3 = __shfl(myS, i + 6 + half);
            h2v v0 = T[(size_t)s0 * 32 + sl], v1 = T[(size_t)s1 * 32 + sl];
            h2v v2 = T[(size_t)s2 * 32 + sl], v3 = T[(size_t)s3 * 32 + sl];
            ax += (float)v0[0] + (float)v1[0] + (float)v2[0] + (float)v3[0];
            ay += (float)v0[1] + (float)v1[1] + (float)v2[1] + (float)v3[1];
        }
        for (; i < m; i += 2) {
            if (i + half < m) {
                int s = __shfl(myS, i + half);
                h2v v = T[(size_t)s * 32 + sl];
                ax += (float)v[0]; ay += (float)v[1];
            }
        }
    }
    ax += __shfl_xor(ax, 32);
    ay += __shfl_xor(ay, 32);
    float di = (cnt > 0) ? 1.0f / (float)cnt : 0.0f;
    h2v rr = ((const h2v*)r2)[(size_t)node * 32 + sl];
    float2 bb = ((const float2*)bl2)[sl];
    float v0 = fmaf(ax, di, bb.x + (float)rr[0]);
    float v1 = fmaf(ay, di, bb.y + (float)rr[1]);
    float ss = v0 * v0 + v1 * v1;
#pragma unroll
    for (int off = 16; off > 0; off >>= 1) ss += __shfl_xor(ss, off);
    float inv = 1.0f / fmaxf(sqrtf(ss), 1e-12f);
    if (half == 0)
        ((float2*)out)[(size_t)node * 32 + sl] = make_float2(v0 * inv, v1 * inv);
}

// ---------------- launch ----------------

extern "C" void kernel_launch(void* const* d_in, const int* in_sizes, int n_in,
                              void* d_out, int out_size, void* d_ws, size_t ws_size,
                              hipStream_t stream) {
    const float* x    = (const float*)d_in[0];
    const int*   ei   = (const int*)d_in[1];
    const float* Wpre = (const float*)d_in[2];
    const float* bpre = (const float*)d_in[3];
    const float* Wl1  = (const float*)d_in[4];
    const float* bl1  = (const float*)d_in[5];
    const float* Wr1  = (const float*)d_in[6];
    const float* Wl2  = (const float*)d_in[7];
    const float* bl2  = (const float*)d_in[8];
    const float* Wr2  = (const float*)d_in[9];
    float* out = (float*)d_out;

    char* w = (char*)d_ws;
    int* counts = (int*)w;  w += (size_t)NN * 4;
    int* cursor = (int*)w;  w += (size_t)NN * 4;
    int* rowp   = (int*)w;  w += (size_t)NN * 4;
    int* bsums  = (int*)w;  w += 256;
    int* col    = (int*)w;  w += (size_t)EE * 4;
    _Float16* WpH  = (_Float16*)w; w += (size_t)256 * 128 * 2;
    _Float16* WpL  = (_Float16*)w; w += (size_t)256 * 128 * 2;
    _Float16* W1lH = (_Float16*)w; w += (size_t)128 * 128 * 2;
    _Float16* W1lL = (_Float16*)w; w += (size_t)128 * 128 * 2;
    _Float16* W1rH = (_Float16*)w; w += (size_t)128 * 128 * 2;
    _Float16* W1rL = (_Float16*)w; w += (size_t)128 * 128 * 2;
    _Float16* W2lH = (_Float16*)w; w += (size_t)128 * 64 * 2;
    _Float16* W2lL = (_Float16*)w; w += (size_t)128 * 64 * 2;
    _Float16* W2rH = (_Float16*)w; w += (size_t)128 * 64 * 2;
    _Float16* W2rL = (_Float16*)w; w += (size_t)128 * 64 * 2;
    _Float16* xh   = (_Float16*)w; w += (size_t)NN * 256 * 2;   // 25.6MB
    _Float16* h0   = (_Float16*)w; w += (size_t)NN * 128 * 2;   // 12.8MB
    _Float16* t1   = (_Float16*)w; w += (size_t)NN * 128 * 2;
    _Float16* r1   = (_Float16*)w; w += (size_t)NN * 128 * 2;
    _Float16* h1   = (_Float16*)w; w += (size_t)NN * 128 * 2;
    _Float16* t2   = (_Float16*)w; w += (size_t)NN * 64 * 2;
    _Float16* r2   = (_Float16*)w; w += (size_t)NN * 64 * 2;

    hipMemsetAsync(counts, 0, (size_t)NN * 8, stream);    // counts + cursor

    dim3 b256(256);
    dim3 gE((EE + 255) / 256);
    k_count<<<gE, b256, 0, stream>>>(ei, counts);
    k_scan_a<<<dim3(NBLK), b256, 0, stream>>>(counts, bsums);
    k_scan_b<<<dim3(1), dim3(64), 0, stream>>>(bsums);
    k_scan_c<<<dim3(NBLK), b256, 0, stream>>>(counts, bsums, rowp);
    k_scatter<<<gE, b256, 0, stream>>>(ei, rowp, cursor, col);

    k_cvt<<<dim3(NN * 256 / 4 / 256), b256, 0, stream>>>(x, xh, NN * 256 / 4);
    k_pack<<<dim3(128), b256, 0, stream>>>(Wpre, WpH, WpL, 256, 128);
    k_pack<<<dim3(64),  b256, 0, stream>>>(Wl1, W1lH, W1lL, 128, 128);
    k_pack<<<dim3(64),  b256, 0, stream>>>(Wr1, W1rH, W1rL, 128, 128);
    k_pack<<<dim3(32),  b256, 0, stream>>>(Wl2, W2lH, W2lL, 128, 64);
    k_pack<<<dim3(32),  b256, 0, stream>>>(Wr2, W2rH, W2rL, 128, 64);

    dim3 gP(GEMM_BLOCKS);
    k_gemm_pre<<<gP, b256, 0, stream>>>(xh, WpH, WpL, bpre, h0);
    k_gemm_dual<128><<<gP, b256, 0, stream>>>(h0, W1lH, W1lL, W1rH, W1rL, t1, r1);
    k_aggr1<<<dim3((NN + 3) / 4), b256, 0, stream>>>(t1, r1, rowp, counts, col, bl1, h1);
    k_gemm_dual<64><<<gP, b256, 0, stream>>>(h1, W2lH, W2lL, W2rH, W2rL, t2, r2);
    k_aggr2<<<dim3((NN + 3) / 4), b256, 0, stream>>>(t2, r2, rowp, counts, col, bl2, out);
}